// Round 1
// 391.402 us; speedup vs baseline: 1.0561x; 1.0561x over previous
//
#include <hip/hip_runtime.h>

#define N 8192
#define D 128
#define MAXNZ 256   // max nonzeros per row we track (mean 82, sigma 9; P(>256) ~ 0)

// Full-wave (64-lane) butterfly reduce; result broadcast to all lanes.
__device__ __forceinline__ float wave_reduce(float p) {
    #pragma unroll
    for (int off = 32; off > 0; off >>= 1)
        p += __shfl_xor(p, off, 64);
    return p;
}

// One wave per row.
// Phase 1: stream A[row,:] with a 4-deep float4 software pipeline (prefetch
//          group it+1 issued before group it is consumed), compact nonzeros
//          (col,val) into LDS via ballot + prefix-popcount.
// Phase 2: 4 dots per iteration with ILP-4 interleaved butterfly reduces;
//          the NEXT group's W-row gathers (and col/val LDS reads) are issued
//          before the current group's shuffle chain, hiding L2 latency.
// Block-reduce partials to partials[blockIdx]; no global atomics.
__global__ __launch_bounds__(256, 6)
void gf_main_kernel(const float* __restrict__ A,
                    const float* __restrict__ W,
                    const float* __restrict__ b,
                    float* __restrict__ partials) {
    __shared__ int   s_col[4][MAXNZ];
    __shared__ float s_val[4][MAXNZ];
    __shared__ float s_bsum[4];

    const int lane = threadIdx.x & 63;
    const int w    = threadIdx.x >> 6;
    const int row  = blockIdx.x * 4 + w;

    const float2 bb = ((const float2*)b)[lane];
    float2 yi = ((const float2*)(W + (size_t)row * D))[lane];
    yi.x += bb.x; yi.y += bb.y;

    // ---- Phase 1: compact nonzeros of this row into LDS (pipelined) ----
    const float4* Arow = (const float4*)(A + (size_t)row * N);
    const unsigned long long lmask = (1ull << lane) - 1ull;

    float4 pf[4];
    #pragma unroll
    for (int k = 0; k < 4; ++k) pf[k] = Arow[k * 64 + lane];

    int cnt = 0;
    for (int it = 0; it < 8; ++it) {          // 8 macro-iters x 4 chunks = 32
        float4 cur[4];
        #pragma unroll
        for (int k = 0; k < 4; ++k) cur[k] = pf[k];
        if (it < 7) {
            #pragma unroll
            for (int k = 0; k < 4; ++k)
                pf[k] = Arow[(it + 1) * 256 + k * 64 + lane];  // issue next group now
        }
        #pragma unroll
        for (int k = 0; k < 4; ++k) {
            const int base_col = (it * 4 + k) * 256 + lane * 4;
            const float av4[4] = {cur[k].x, cur[k].y, cur[k].z, cur[k].w};
            #pragma unroll
            for (int q = 0; q < 4; ++q) {
                const unsigned long long m = __ballot(av4[q] > 0.0f);
                if (av4[q] > 0.0f) {
                    const int pos = cnt + __popcll(m & lmask);
                    if (pos < MAXNZ) {
                        s_col[w][pos] = base_col + q;
                        s_val[w][pos] = av4[q];
                    }
                }
                cnt += __popcll(m);
            }
        }
    }
    if (cnt > MAXNZ) cnt = MAXNZ;
    __syncthreads();   // order LDS writes before cross-lane reads

    // ---- Phase 2: 4 dots per iteration, one-group-ahead gather prefetch ----
    float acc = 0.0f;
    float2 yjn[4];
    float  avn[4];
    #pragma unroll
    for (int k = 0; k < 4; ++k) {             // prefetch group 0
        const bool valid = k < cnt;
        const int  idx   = valid ? k : 0;
        const int  j     = s_col[w][idx];     // wave-uniform broadcast read
        avn[k]           = valid ? s_val[w][idx] : 0.0f;
        yjn[k]           = ((const float2*)(W + (size_t)j * D))[lane];
    }

    for (int t = 0; t < cnt; t += 4) {
        float2 yj[4];
        float  av[4];
        #pragma unroll
        for (int k = 0; k < 4; ++k) { yj[k] = yjn[k]; av[k] = avn[k]; }

        if (t + 4 < cnt) {                    // issue next group's gathers now
            #pragma unroll
            for (int k = 0; k < 4; ++k) {
                const bool valid = (t + 4 + k) < cnt;
                const int  idx   = valid ? (t + 4 + k) : 0;
                const int  j     = s_col[w][idx];
                avn[k]           = valid ? s_val[w][idx] : 0.0f;
                yjn[k]           = ((const float2*)(W + (size_t)j * D))[lane];
            }
        }

        float p[4];
        #pragma unroll
        for (int k = 0; k < 4; ++k)
            p[k] = yi.x * (yj[k].x + bb.x) + yi.y * (yj[k].y + bb.y);

        #pragma unroll
        for (int off = 32; off > 0; off >>= 1) {
            #pragma unroll
            for (int k = 0; k < 4; ++k)
                p[k] += __shfl_xor(p[k], off, 64);
        }

        #pragma unroll
        for (int k = 0; k < 4; ++k) {
            if ((t + k) < cnt) {
                const float r = av[k] - p[k];
                acc += r * r;                 // wave-uniform
            }
        }
    }

    // ---- Epilogue: per-row totals, block reduce, one store per block ----
    const float reg = wave_reduce(yi.x * yi.x + yi.y * yi.y);
    const float total = 0.5f * acc + 0.05f * reg;
    if (lane == 0) s_bsum[w] = total;
    __syncthreads();
    if (threadIdx.x == 0)
        partials[blockIdx.x] = s_bsum[0] + s_bsum[1] + s_bsum[2] + s_bsum[3];
}

// Reduce 2048 block partials -> out[0]. One block, 256 threads.
__global__ __launch_bounds__(256)
void gf_reduce_kernel(const float* __restrict__ partials, float* __restrict__ out) {
    __shared__ float s_ws[4];
    const int lane = threadIdx.x & 63;
    const int w    = threadIdx.x >> 6;
    float s = 0.0f;
    for (int i = threadIdx.x; i < N / 4; i += 256) s += partials[i];
    s = wave_reduce(s);
    if (lane == 0) s_ws[w] = s;
    __syncthreads();
    if (threadIdx.x == 0) out[0] = s_ws[0] + s_ws[1] + s_ws[2] + s_ws[3];
}

extern "C" void kernel_launch(void* const* d_in, const int* in_sizes, int n_in,
                              void* d_out, int out_size, void* d_ws, size_t ws_size,
                              hipStream_t stream) {
    const float* A = (const float*)d_in[0];
    const float* W = (const float*)d_in[1];
    const float* b = (const float*)d_in[2];
    float* out = (float*)d_out;
    float* partials = (float*)d_ws;    // 2048 floats = 8 KB

    gf_main_kernel<<<dim3(N / 4), dim3(256), 0, stream>>>(A, W, b, partials);
    gf_reduce_kernel<<<dim3(1), dim3(256), 0, stream>>>(partials, out);
}

// Round 3
// 378.797 us; speedup vs baseline: 1.0913x; 1.0333x over previous
//
#include <hip/hip_runtime.h>

#define N 8192
#define D 128
#define MAXNZ 256   // max nonzeros per row we track (mean 82, sigma 9; P(>256) ~ 0)

// Native clang vector type — __builtin_nontemporal_load requires a pointer to
// scalar/vector-of-scalar, not HIP's float4 class.
typedef float nt_float4 __attribute__((ext_vector_type(4)));

// Full-wave (64-lane) butterfly reduce; result broadcast to all lanes.
__device__ __forceinline__ float wave_reduce(float p) {
    #pragma unroll
    for (int off = 32; off > 0; off >>= 1)
        p += __shfl_xor(p, off, 64);
    return p;
}

// One wave per row.
// Phase 1: stream A[row,:] NON-TEMPORALLY (A is read exactly once; without nt
//          its 256 MB stream thrashes L2+L3 and evicts W, turning phase-2
//          gathers into ~900-cyc HBM misses) with a 4-deep float4 pipeline,
//          compact nonzeros (col,val) into LDS via ballot + prefix-popcount.
// Phase 2: 4 dots per iteration with ILP-4 interleaved butterfly reduces;
//          next group's W-row gathers issued before the current group's
//          shuffle chain — enough to hide an L2-hit (~200 cyc) gather.
// Block-reduce partials to partials[blockIdx]; no global atomics.
__global__ __launch_bounds__(256, 6)
void gf_main_kernel(const float* __restrict__ A,
                    const float* __restrict__ W,
                    const float* __restrict__ b,
                    float* __restrict__ partials) {
    __shared__ int   s_col[4][MAXNZ];
    __shared__ float s_val[4][MAXNZ];
    __shared__ float s_bsum[4];

    const int lane = threadIdx.x & 63;
    const int w    = threadIdx.x >> 6;
    const int row  = blockIdx.x * 4 + w;

    const float2 bb = ((const float2*)b)[lane];
    float2 yi = ((const float2*)(W + (size_t)row * D))[lane];
    yi.x += bb.x; yi.y += bb.y;

    // ---- Phase 1: compact nonzeros of this row into LDS (pipelined, nt) ----
    const nt_float4* Arow = (const nt_float4*)(A + (size_t)row * N);
    const unsigned long long lmask = (1ull << lane) - 1ull;

    nt_float4 pf[4];
    #pragma unroll
    for (int k = 0; k < 4; ++k) pf[k] = __builtin_nontemporal_load(&Arow[k * 64 + lane]);

    int cnt = 0;
    for (int it = 0; it < 8; ++it) {          // 8 macro-iters x 4 chunks = 32
        nt_float4 cur[4];
        #pragma unroll
        for (int k = 0; k < 4; ++k) cur[k] = pf[k];
        if (it < 7) {
            #pragma unroll
            for (int k = 0; k < 4; ++k)
                pf[k] = __builtin_nontemporal_load(&Arow[(it + 1) * 256 + k * 64 + lane]);
        }
        #pragma unroll
        for (int k = 0; k < 4; ++k) {
            const int base_col = (it * 4 + k) * 256 + lane * 4;
            const float av4[4] = {cur[k].x, cur[k].y, cur[k].z, cur[k].w};
            #pragma unroll
            for (int q = 0; q < 4; ++q) {
                const unsigned long long m = __ballot(av4[q] > 0.0f);
                if (av4[q] > 0.0f) {
                    const int pos = cnt + __popcll(m & lmask);
                    if (pos < MAXNZ) {
                        s_col[w][pos] = base_col + q;
                        s_val[w][pos] = av4[q];
                    }
                }
                cnt += __popcll(m);
            }
        }
    }
    if (cnt > MAXNZ) cnt = MAXNZ;
    __syncthreads();   // order LDS writes before cross-lane reads

    // ---- Phase 2: 4 dots per iteration, one-group-ahead gather prefetch ----
    float acc = 0.0f;
    float2 yjn[4];
    float  avn[4];
    #pragma unroll
    for (int k = 0; k < 4; ++k) {             // prefetch group 0
        const bool valid = k < cnt;
        const int  idx   = valid ? k : 0;
        const int  j     = s_col[w][idx];     // wave-uniform broadcast read
        avn[k]           = valid ? s_val[w][idx] : 0.0f;
        yjn[k]           = ((const float2*)(W + (size_t)j * D))[lane];
    }

    for (int t = 0; t < cnt; t += 4) {
        float2 yj[4];
        float  av[4];
        #pragma unroll
        for (int k = 0; k < 4; ++k) { yj[k] = yjn[k]; av[k] = avn[k]; }

        if (t + 4 < cnt) {                    // issue next group's gathers now
            #pragma unroll
            for (int k = 0; k < 4; ++k) {
                const bool valid = (t + 4 + k) < cnt;
                const int  idx   = valid ? (t + 4 + k) : 0;
                const int  j     = s_col[w][idx];
                avn[k]           = valid ? s_val[w][idx] : 0.0f;
                yjn[k]           = ((const float2*)(W + (size_t)j * D))[lane];
            }
        }

        float p[4];
        #pragma unroll
        for (int k = 0; k < 4; ++k)
            p[k] = yi.x * (yj[k].x + bb.x) + yi.y * (yj[k].y + bb.y);

        #pragma unroll
        for (int off = 32; off > 0; off >>= 1) {
            #pragma unroll
            for (int k = 0; k < 4; ++k)
                p[k] += __shfl_xor(p[k], off, 64);
        }

        #pragma unroll
        for (int k = 0; k < 4; ++k) {
            if ((t + k) < cnt) {
                const float r = av[k] - p[k];
                acc += r * r;                 // wave-uniform
            }
        }
    }

    // ---- Epilogue: per-row totals, block reduce, one store per block ----
    const float reg = wave_reduce(yi.x * yi.x + yi.y * yi.y);
    const float total = 0.5f * acc + 0.05f * reg;
    if (lane == 0) s_bsum[w] = total;
    __syncthreads();
    if (threadIdx.x == 0)
        partials[blockIdx.x] = s_bsum[0] + s_bsum[1] + s_bsum[2] + s_bsum[3];
}

// Reduce 2048 block partials -> out[0]. One block, 256 threads.
__global__ __launch_bounds__(256)
void gf_reduce_kernel(const float* __restrict__ partials, float* __restrict__ out) {
    __shared__ float s_ws[4];
    const int lane = threadIdx.x & 63;
    const int w    = threadIdx.x >> 6;
    float s = 0.0f;
    for (int i = threadIdx.x; i < N / 4; i += 256) s += partials[i];
    s = wave_reduce(s);
    if (lane == 0) s_ws[w] = s;
    __syncthreads();
    if (threadIdx.x == 0) out[0] = s_ws[0] + s_ws[1] + s_ws[2] + s_ws[3];
}

extern "C" void kernel_launch(void* const* d_in, const int* in_sizes, int n_in,
                              void* d_out, int out_size, void* d_ws, size_t ws_size,
                              hipStream_t stream) {
    const float* A = (const float*)d_in[0];
    const float* W = (const float*)d_in[1];
    const float* b = (const float*)d_in[2];
    float* out = (float*)d_out;
    float* partials = (float*)d_ws;    // 2048 floats = 8 KB

    gf_main_kernel<<<dim3(N / 4), dim3(256), 0, stream>>>(A, W, b, partials);
    gf_reduce_kernel<<<dim3(1), dim3(256), 0, stream>>>(partials, out);
}